// Round 5
// baseline (213.113 us; speedup 1.0000x reference)
//
#include <hip/hip_runtime.h>
#include <hip/hip_bf16.h>

typedef short short8 __attribute__((ext_vector_type(8)));
typedef float float4v __attribute__((ext_vector_type(4)));

__device__ __forceinline__ ushort f2bf(float f) {
  union { float f; unsigned int u; } x;
  x.f = f;
  unsigned int r = x.u + 0x7FFFu + ((x.u >> 16) & 1u);  // RNE
  return (ushort)(r >> 16);
}
// decoding-order sort key, same op order as reference (all fp32)
__device__ __forceinline__ float keyf(const float* cm, const float* mk,
                                      const float* zz, int i) {
  return (cm[i] * mk[i] + 1e-4f) * fabsf(zz[i]);
}

// ---------------------------------------------------------------------------
// Single fused kernel, fp32 in / fp32 out. Grid 512 x 256.
// Each block handles 8 nodes (4 waves x 2 iterations).
// Structure: stage We2 into LDS in MFMA-B-fragment order; compute the
// collapsed layer-1 constants and T = W_s @ Wl2[128:,:] in LDS; then per
// wave: ee = E_rows @ We2 via mfma_f32_16x16x32_bf16, fused
// leakyrelu/score/softmax/aggregate/logits/log_softmax.
// ---------------------------------------------------------------------------
__global__ __launch_bounds__(256) void pg5_fused(
    const float* __restrict__ E, const int* __restrict__ E_idx,
    const int* __restrict__ S, const float* __restrict__ mask,
    const float* __restrict__ chain_M, const float* __restrict__ z,
    const float* __restrict__ bl1, const float* __restrict__ bo1,
    const float* __restrict__ Wl2, const float* __restrict__ bl2,
    const float* __restrict__ Wr2, const float* __restrict__ br2,
    const float* __restrict__ We2, const float* __restrict__ be2,
    const float* __restrict__ a2, const float* __restrict__ bo2,
    const float* __restrict__ W_s, const float* __restrict__ W_out,
    const float* __restrict__ b_out, float* __restrict__ out)
{
  __shared__ __align__(16) short ldsW[16384];   // swizzled We2 (B-frag layout)
  __shared__ float ldsT[21 * 128];
  __shared__ float ldsD[128], ldsC[128], ldsO[128], ldsA2[128];
  __shared__ float ldswk[4][32];
  __shared__ int   ldsrow[4][32];
  __shared__ float ldscoef[4][32];
  __shared__ float ldsout[4][128];

  const int tid  = threadIdx.x;
  const int wave = tid >> 6;
  const int lane = tid & 63;
  const int quad = lane >> 4;
  const int lid  = lane & 15;
  const int base = blockIdx.x * 8;

  // --- stage We2 (fp32 -> bf16) swizzled so that for tile (q,t), lane L reads
  //     contiguous 16B holding We2[q*32 + (L>>4)*8 + j][t*16 + (L&15)], j=0..7
  for (int s = tid * 8; s < 16384; s += 2048) {
    const int i  = s >> 7, c0 = s & 127;
    const int q  = i >> 5, i5 = i & 31;
    const int lh = i5 >> 3, j = i5 & 7;
    const float* w = We2 + s;
#pragma unroll
    for (int u = 0; u < 8; u++) {
      const int c = c0 + u, t = c >> 4, cl = c & 15;
      ldsW[(((q * 8 + t) * 64) + lh * 16 + cl) * 8 + j] = (short)f2bf(w[u]);
    }
  }
  // --- T[v][c] = sum_h W_s[v,h] * Wl2[128+h, c]   (fp32)
  for (int idx = tid; idx < 21 * 128; idx += 256) {
    const int v = idx >> 7, c = idx & 127;
    float acc = 0.f;
    for (int h = 0; h < 128; h++)
      acc += W_s[v * 128 + h] * Wl2[(128 + h) * 128 + c];
    ldsT[idx] = acc;
  }
  // --- collapsed constants: layer-1 output is the constant vector bl1+bo1
  if (tid < 128) {
    const int c = tid;
    float cl0 = 0.f, cr0 = 0.f;
    for (int i = 0; i < 128; i++) {
      const float s = bl1[i] + bo1[i];
      cl0 += s * Wl2[i * 128 + c];
      cr0 += s * Wr2[i * 128 + c];
    }
    ldsD[c]  = be2[c] + bl2[c] + br2[c] + cr0;  // const part of xl+xr+ee
    ldsC[c]  = cl0;
    ldsO[c]  = bl2[c] + bo2[c];
    ldsA2[c] = a2[c];
  }
  __syncthreads();

  for (int it = 0; it < 2; it++) {
    const int n = base + it * 4 + wave;
    const float maskn = mask[n];
    const float keyn  = keyf(chain_M, mask, z, n);
    if (lane < 32) {
      const int j = E_idx[n * 32 + lane];
      const float kj = keyf(chain_M, mask, z, j);
      // stable argsort: j ordered before n  <=>  (key[j], j) <lex (key[n], n)
      const int before = (kj < keyn) || (kj == keyn && j < n);
      ldswk[wave][lane]  = before ? maskn : 0.f;
      ldsrow[wave][lane] = S[j];
    }
    float dv[8], a2v[8];
#pragma unroll
    for (int t = 0; t < 8; t++) {
      const int c = t * 16 + lid;
      dv[t]  = ldsD[c] + maskn * ldsC[c];
      a2v[t] = ldsA2[c];
    }
    // A fragments from E (fp32 -> bf16): A[m=lid][k = q*32 + quad*8 + j]
    short8 afr[2][4];
#pragma unroll
    for (int g = 0; g < 2; g++) {
      const float* erow = E + (size_t)(n * 32 + g * 16 + lid) * 128 + quad * 8;
#pragma unroll
      for (int q = 0; q < 4; q++) {
        short8 v;
#pragma unroll
        for (int u = 0; u < 8; u++) v[u] = (short)f2bf(erow[q * 32 + u]);
        afr[g][q] = v;
      }
    }
    __syncthreads();

    float sreg[2][4];
#pragma unroll
    for (int g = 0; g < 2; g++) {
      float part[4] = {0.f, 0.f, 0.f, 0.f};
#pragma unroll
      for (int t = 0; t < 8; t++) {
        float4v acc = {0.f, 0.f, 0.f, 0.f};
#pragma unroll
        for (int q = 0; q < 4; q++) {
          const short8 bfr = *(const short8*)&ldsW[(((q * 8 + t) * 64) + lane) * 8];
          acc = __builtin_amdgcn_mfma_f32_16x16x32_bf16(afr[g][q], bfr, acc, 0, 0, 0);
        }
        const int c = t * 16 + lid;
#pragma unroll
        for (int r = 0; r < 4; r++) {
          const int kk = g * 16 + quad * 4 + r;
          float val = acc[r] + dv[t] +
                      ldswk[wave][kk] * ldsT[ldsrow[wave][kk] * 128 + c];
          val = fmaxf(val, 0.f) + 0.2f * fminf(val, 0.f);   // leaky_relu(0.2)
          part[r] = fmaf(val, a2v[t], part[r]);
        }
      }
#pragma unroll
      for (int r = 0; r < 4; r++) {
        float v = part[r];
        v += __shfl_xor(v, 1);
        v += __shfl_xor(v, 2);
        v += __shfl_xor(v, 4);
        v += __shfl_xor(v, 8);
        sreg[g][r] = v;   // score for edge k = g*16 + quad*4 + r
      }
    }
    // softmax over the 32 neighbor scores
    float mx = -1e30f;
#pragma unroll
    for (int g = 0; g < 2; g++)
#pragma unroll
      for (int r = 0; r < 4; r++) mx = fmaxf(mx, sreg[g][r]);
    mx = fmaxf(mx, __shfl_xor(mx, 16));
    mx = fmaxf(mx, __shfl_xor(mx, 32));
    float eg[2][4];
    float esum = 0.f;
#pragma unroll
    for (int g = 0; g < 2; g++)
#pragma unroll
      for (int r = 0; r < 4; r++) {
        eg[g][r] = expf(sreg[g][r] - mx);
        esum += eg[g][r];
      }
    esum += __shfl_xor(esum, 16);
    esum += __shfl_xor(esum, 32);
    const float inv = 1.f / esum;
    if (lid == 0) {
#pragma unroll
      for (int g = 0; g < 2; g++)
#pragma unroll
        for (int r = 0; r < 4; r++) {
          const int kk = g * 16 + quad * 4 + r;
          ldscoef[wave][kk] = eg[g][r] * inv * ldswk[wave][kk];
        }
    }
    __syncthreads();

    // out_vec[c] = O[c] + maskn*cl0[c] + sum_k coef_k * T[S_jk][c]
    float o0 = ldsO[lane]      + maskn * ldsC[lane];
    float o1 = ldsO[lane + 64] + maskn * ldsC[lane + 64];
#pragma unroll 4
    for (int kk = 0; kk < 32; kk++) {
      const float cf = ldscoef[wave][kk];
      const int row = ldsrow[wave][kk] * 128;
      o0 = fmaf(cf, ldsT[row + lane], o0);
      o1 = fmaf(cf, ldsT[row + lane + 64], o1);
    }
    ldsout[wave][lane] = o0;
    ldsout[wave][lane + 64] = o1;
    __syncthreads();

    // logits (lanes 0..20) + log_softmax over V=21 ; fp32 output
    float lg = (lane < 21) ? b_out[lane] : -1e30f;
    if (lane < 21) {
      for (int c = 0; c < 128; c++)
        lg = fmaf(ldsout[wave][c], W_out[c * 21 + lane], lg);
    }
    float lmx = lg;
    lmx = fmaxf(lmx, __shfl_xor(lmx, 1));
    lmx = fmaxf(lmx, __shfl_xor(lmx, 2));
    lmx = fmaxf(lmx, __shfl_xor(lmx, 4));
    lmx = fmaxf(lmx, __shfl_xor(lmx, 8));
    lmx = fmaxf(lmx, __shfl_xor(lmx, 16));
    float ex = (lane < 21) ? expf(lg - lmx) : 0.f;
    float es = ex;
    es += __shfl_xor(es, 1);
    es += __shfl_xor(es, 2);
    es += __shfl_xor(es, 4);
    es += __shfl_xor(es, 8);
    es += __shfl_xor(es, 16);
    if (lane < 21)
      out[n * 21 + lane] = lg - lmx - logf(es);
    __syncthreads();
  }
}

extern "C" void kernel_launch(void* const* d_in, const int* in_sizes, int n_in,
                              void* d_out, int out_size, void* d_ws, size_t ws_size,
                              hipStream_t stream)
{
  pg5_fused<<<512, 256, 0, stream>>>(
      (const float*)d_in[0],   // E
      (const int*)d_in[1],     // E_idx
      (const int*)d_in[2],     // S
      (const float*)d_in[3],   // mask
      (const float*)d_in[4],   // chain_M
      (const float*)d_in[5],   // z
      (const float*)d_in[7],   // bl1
      (const float*)d_in[13],  // bo1
      (const float*)d_in[14],  // Wl2
      (const float*)d_in[15],  // bl2
      (const float*)d_in[16],  // Wr2
      (const float*)d_in[17],  // br2
      (const float*)d_in[18],  // We2
      (const float*)d_in[19],  // be2
      (const float*)d_in[20],  // a2
      (const float*)d_in[21],  // bo2
      (const float*)d_in[22],  // W_s
      (const float*)d_in[23],  // W_out
      (const float*)d_in[24],  // b_out
      (float*)d_out);
}

// Round 6
// 171.939 us; speedup vs baseline: 1.2395x; 1.2395x over previous
//
#include <hip/hip_runtime.h>
#include <hip/hip_bf16.h>

typedef short short8 __attribute__((ext_vector_type(8)));
typedef float float4v __attribute__((ext_vector_type(4)));

// ws float-region offsets (float* F = (float*)ws + 8192; first 32KB = swizzled We2 shorts)
#define WS_T   0
#define WS_D   2688
#define WS_C   2816
#define WS_O   2944
#define WS_A2  3072
#define WS_KEY 3200

__device__ __forceinline__ unsigned int pack2bf(float a, float b) {
  // two fp32 -> packed bf16 pair (round-half-up; differs from RNE only on exact ties)
  union { float f; unsigned int u; } xa, xb;
  xa.f = a; xb.f = b;
  return ((xa.u + 0x8000u) >> 16) | ((xb.u + 0x8000u) & 0xFFFF0000u);
}

// ---------------------------------------------------------------------------
// Prologue (grid 38 x 256): block 0 = We2 swizzle (bf16, MFMA-B-frag order) +
// collapsed constants; blocks 1..21 = T[v] = W_s[v] @ Wl2[128:,:]; blocks
// 22..37 = decoding-order keys.
// ---------------------------------------------------------------------------
__global__ __launch_bounds__(256) void pg6_pre(
    const float* __restrict__ Wl2, const float* __restrict__ Wr2,
    const float* __restrict__ We2, const float* __restrict__ bl1,
    const float* __restrict__ bl2, const float* __restrict__ br2,
    const float* __restrict__ be2, const float* __restrict__ a2,
    const float* __restrict__ bo1, const float* __restrict__ bo2,
    const float* __restrict__ W_s, const float* __restrict__ mask,
    const float* __restrict__ chain_M, const float* __restrict__ z,
    void* __restrict__ ws)
{
  short* wsW = (short*)ws;
  float* F = (float*)ws + 8192;
  const int b = blockIdx.x, tid = threadIdx.x;
  if (b == 0) {
    for (int s = tid; s < 16384; s += 256) {
      const int row = s >> 7, c = s & 127;
      const int q = row >> 5, lh = (row & 31) >> 3, j = row & 7;
      const int t = c >> 4, cl = c & 15;
      union { float f; unsigned int u; } x; x.f = We2[s];
      const unsigned int r = x.u + 0x7FFFu + ((x.u >> 16) & 1u);  // RNE
      wsW[(((q * 8 + t) * 64) + lh * 16 + cl) * 8 + j] = (short)(r >> 16);
    }
    if (tid < 128) {
      const int c = tid;
      float cl0 = 0.f, cr0 = 0.f;
      for (int i = 0; i < 128; i++) {
        const float s = bl1[i] + bo1[i];     // layer-1 output (constant vector)
        cl0 += s * Wl2[i * 128 + c];
        cr0 += s * Wr2[i * 128 + c];
      }
      F[WS_D + c]  = be2[c] + bl2[c] + br2[c] + cr0;
      F[WS_C + c]  = cl0;
      F[WS_O + c]  = bl2[c] + bo2[c];
      F[WS_A2 + c] = a2[c];
    }
  } else if (b <= 21) {
    const int v = b - 1;
    if (tid < 128) {
      const int c = tid;
      float acc = 0.f;
      for (int h = 0; h < 128; h++)
        acc += W_s[v * 128 + h] * Wl2[(128 + h) * 128 + c];
      F[WS_T + v * 128 + c] = acc;
    }
  } else {
    const int n = (b - 22) * 256 + tid;
    F[WS_KEY + n] = (chain_M[n] * mask[n] + 1e-4f) * fabsf(z[n]);
  }
}

// ---------------------------------------------------------------------------
// Main (grid 1024 x 256): 4 nodes/block, one wave per node, single iteration,
// 2 barriers total. ee = E_rows @ We2 via mfma_f32_16x16x32_bf16; fused
// leakyrelu/score/softmax/aggregate/logits/log_softmax. T padded to 132.
// ---------------------------------------------------------------------------
__global__ __launch_bounds__(256) void pg6_main(
    const float* __restrict__ E, const int* __restrict__ E_idx,
    const int* __restrict__ S, const float* __restrict__ mask,
    const float* __restrict__ W_out, const float* __restrict__ b_out,
    const void* __restrict__ ws, float* __restrict__ out)
{
  __shared__ __align__(16) short ldsW[16384];   // We2, B-frag order (32KB)
  __shared__ float ldsTp[21 * 132];             // T padded stride 132
  __shared__ float ldsD[128], ldsC[128], ldsO[128], ldsA2[128];
  __shared__ float ldswk[4][32];
  __shared__ int   ldsrv[4][32];
  __shared__ float ldsout[4][128];

  const short* wsW = (const short*)ws;
  const float* F = (const float*)ws + 8192;
  const int tid  = threadIdx.x;
  const int wave = tid >> 6;
  const int lane = tid & 63;
  const int quad = lane >> 4;
  const int lid  = lane & 15;
  const int nb   = blockIdx.x * 4;
  const int n    = nb + wave;
  const float maskn = mask[n];

  // --- A fragments (prefetch before barrier): A[m=lid][k=q*32+quad*8+j]
  short8 afr[2][4];
#pragma unroll
  for (int g = 0; g < 2; g++) {
    const float* erow = E + (size_t)(n * 32 + g * 16 + lid) * 128 + quad * 8;
#pragma unroll
    for (int q = 0; q < 4; q++) {
      const float4 A = *(const float4*)(erow + q * 32);
      const float4 B = *(const float4*)(erow + q * 32 + 4);
      union { short8 s; unsigned int u[4]; } v;
      v.u[0] = pack2bf(A.x, A.y);
      v.u[1] = pack2bf(A.z, A.w);
      v.u[2] = pack2bf(B.x, B.y);
      v.u[3] = pack2bf(B.z, B.w);
      afr[g][q] = v.s;
    }
  }

  // --- stage from ws (consecutive b128 copies, conflict-free)
  for (int i = tid * 8; i < 16384; i += 2048)
    *(uint4*)&ldsW[i] = *(const uint4*)&wsW[i];
  for (int idx = tid; idx < 2688; idx += 256) {
    const int v = idx >> 7, c = idx & 127;
    ldsTp[v * 132 + c] = F[WS_T + idx];
  }
  if (tid < 128) {
    ldsD[tid]  = F[WS_D + tid];
    ldsC[tid]  = F[WS_C + tid];
    ldsO[tid]  = F[WS_O + tid];
    ldsA2[tid] = F[WS_A2 + tid];
  }
  if (tid < 128) {   // per-edge mask_bw + S gather for the block's 4 nodes
    const int w = tid >> 5, k = tid & 31, nn = nb + w;
    const int j = E_idx[nn * 32 + k];
    const float keyn = F[WS_KEY + nn], kj = F[WS_KEY + j];
    // stable argsort: j ordered before nn  <=>  (key[j], j) <lex (key[nn], nn)
    const int before = (kj < keyn) || (kj == keyn && j < nn);
    ldswk[w][k] = before ? mask[nn] : 0.f;
    ldsrv[w][k] = S[j];
  }
  __syncthreads();

  float dv[8], a2v[8];
#pragma unroll
  for (int t = 0; t < 8; t++) {
    const int c = t * 16 + lid;
    dv[t]  = ldsD[c] + maskn * ldsC[c];
    a2v[t] = ldsA2[c];
  }
  int rows[2][4]; float wks[2][4];
#pragma unroll
  for (int g = 0; g < 2; g++)
#pragma unroll
    for (int r = 0; r < 4; r++) {
      const int kk = g * 16 + quad * 4 + r;
      rows[g][r] = ldsrv[wave][kk] * 132;
      wks[g][r]  = ldswk[wave][kk];
    }

  // --- MFMA + fused leakyrelu/score
  float sreg[2][4];
#pragma unroll
  for (int g = 0; g < 2; g++) {
    float part[4] = {0.f, 0.f, 0.f, 0.f};
#pragma unroll
    for (int t = 0; t < 8; t++) {
      float4v acc = {0.f, 0.f, 0.f, 0.f};
#pragma unroll
      for (int q = 0; q < 4; q++) {
        const short8 bfr = *(const short8*)&ldsW[(((q * 8 + t) * 64) + lane) * 8];
        acc = __builtin_amdgcn_mfma_f32_16x16x32_bf16(afr[g][q], bfr, acc, 0, 0, 0);
      }
      const int c = t * 16 + lid;
#pragma unroll
      for (int r = 0; r < 4; r++) {
        float val = acc[r] + dv[t] + wks[g][r] * ldsTp[rows[g][r] + c];
        val = fmaxf(val, 0.f) + 0.2f * fminf(val, 0.f);   // leaky_relu(0.2)
        part[r] = fmaf(val, a2v[t], part[r]);
      }
    }
#pragma unroll
    for (int r = 0; r < 4; r++) {
      float v = part[r];
      v += __shfl_xor(v, 1);
      v += __shfl_xor(v, 2);
      v += __shfl_xor(v, 4);
      v += __shfl_xor(v, 8);
      sreg[g][r] = v;   // score for edge kk = g*16 + quad*4 + r (uniform in quad)
    }
  }

  // --- softmax over 32 neighbor scores
  float mx = -1e30f;
#pragma unroll
  for (int g = 0; g < 2; g++)
#pragma unroll
    for (int r = 0; r < 4; r++) mx = fmaxf(mx, sreg[g][r]);
  mx = fmaxf(mx, __shfl_xor(mx, 16));
  mx = fmaxf(mx, __shfl_xor(mx, 32));
  float eg[2][4], esum = 0.f;
#pragma unroll
  for (int g = 0; g < 2; g++)
#pragma unroll
    for (int r = 0; r < 4; r++) {
      eg[g][r] = expf(sreg[g][r] - mx);
      esum += eg[g][r];
    }
  esum += __shfl_xor(esum, 16);
  esum += __shfl_xor(esum, 32);
  const float inv = 1.f / esum;
  float cg[2][4];
#pragma unroll
  for (int g = 0; g < 2; g++)
#pragma unroll
    for (int r = 0; r < 4; r++) cg[g][r] = eg[g][r] * inv * wks[g][r];

  // --- aggregation: out_vec[c] = O + maskn*cl0 + sum_k coef_k * T[S_jk][c]
  float o0 = ldsO[lane]      + maskn * ldsC[lane];
  float o1 = ldsO[lane + 64] + maskn * ldsC[lane + 64];
#pragma unroll
  for (int kk = 0; kk < 32; kk++) {
    const int g = kk >> 4, sq = (kk >> 2) & 3, r = kk & 3;
    const float cf = __shfl(cg[g][r], sq * 16);   // broadcast from source quad
    const int row = ldsrv[wave][kk] * 132;
    o0 = fmaf(cf, ldsTp[row + lane], o0);
    o1 = fmaf(cf, ldsTp[row + lane + 64], o1);
  }
  ldsout[wave][lane]      = o0;
  ldsout[wave][lane + 64] = o1;
  __syncthreads();

  // --- logits (lanes 0..20) + log_softmax over V=21, 4-way unrolled
  float l0 = 0.f, l1 = 0.f, l2 = 0.f, l3 = 0.f;
  if (lane < 21) {
    const float* wo = W_out + lane;
#pragma unroll 8
    for (int c = 0; c < 128; c += 4) {
      l0 = fmaf(ldsout[wave][c],     wo[c * 21],       l0);
      l1 = fmaf(ldsout[wave][c + 1], wo[(c + 1) * 21], l1);
      l2 = fmaf(ldsout[wave][c + 2], wo[(c + 2) * 21], l2);
      l3 = fmaf(ldsout[wave][c + 3], wo[(c + 3) * 21], l3);
    }
  }
  float lg = (lane < 21) ? (b_out[lane] + ((l0 + l1) + (l2 + l3))) : -1e30f;
  float lmx = lg;
  lmx = fmaxf(lmx, __shfl_xor(lmx, 1));
  lmx = fmaxf(lmx, __shfl_xor(lmx, 2));
  lmx = fmaxf(lmx, __shfl_xor(lmx, 4));
  lmx = fmaxf(lmx, __shfl_xor(lmx, 8));
  lmx = fmaxf(lmx, __shfl_xor(lmx, 16));
  float ex = (lane < 21) ? expf(lg - lmx) : 0.f;
  float es = ex;
  es += __shfl_xor(es, 1);
  es += __shfl_xor(es, 2);
  es += __shfl_xor(es, 4);
  es += __shfl_xor(es, 8);
  es += __shfl_xor(es, 16);
  if (lane < 21)
    out[n * 21 + lane] = lg - lmx - logf(es);
}

extern "C" void kernel_launch(void* const* d_in, const int* in_sizes, int n_in,
                              void* d_out, int out_size, void* d_ws, size_t ws_size,
                              hipStream_t stream)
{
  const float* E       = (const float*)d_in[0];
  const int*   E_idx   = (const int*)d_in[1];
  const int*   S       = (const int*)d_in[2];
  const float* mask    = (const float*)d_in[3];
  const float* chain_M = (const float*)d_in[4];
  const float* z       = (const float*)d_in[5];
  const float* bl1     = (const float*)d_in[7];
  const float* bo1     = (const float*)d_in[13];
  const float* Wl2     = (const float*)d_in[14];
  const float* bl2     = (const float*)d_in[15];
  const float* Wr2     = (const float*)d_in[16];
  const float* br2     = (const float*)d_in[17];
  const float* We2     = (const float*)d_in[18];
  const float* be2     = (const float*)d_in[19];
  const float* a2      = (const float*)d_in[20];
  const float* bo2     = (const float*)d_in[21];
  const float* W_s     = (const float*)d_in[22];
  const float* W_out   = (const float*)d_in[23];
  const float* b_out   = (const float*)d_in[24];

  pg6_pre<<<38, 256, 0, stream>>>(Wl2, Wr2, We2, bl1, bl2, br2, be2, a2,
                                  bo1, bo2, W_s, mask, chain_M, z, d_ws);
  pg6_main<<<1024, 256, 0, stream>>>(E, E_idx, S, mask, W_out, b_out, d_ws,
                                     (float*)d_out);
}